// Round 1
// baseline (13248.233 us; speedup 1.0000x reference)
//
#include <hip/hip_runtime.h>
#include <hip/hip_bf16.h>

#define DIM 2048
#define BM 128
#define BN 128
#define BK 16

// Monotone float->uint map; pack (val, col) so u64 max = (max val, first col on ties)
__device__ __forceinline__ unsigned long long pack_key(float v, unsigned int col) {
    unsigned int b = __float_as_uint(v);
    b ^= (unsigned int)(((int)b >> 31)) | 0x80000000u;
    return ((unsigned long long)b << 32) | (unsigned long long)(~col);
}

__global__ void vocab_invnorm_kernel(const float* __restrict__ Vg,
                                     float* __restrict__ invnorm) {
    const int v = blockIdx.x;
    const int t = threadIdx.x;
    const float* row = Vg + (size_t)v * DIM;
    float4 f0 = *reinterpret_cast<const float4*>(row + t * 8);
    float4 f1 = *reinterpret_cast<const float4*>(row + t * 8 + 4);
    float s = f0.x*f0.x + f0.y*f0.y + f0.z*f0.z + f0.w*f0.w
            + f1.x*f1.x + f1.y*f1.y + f1.z*f1.z + f1.w*f1.w;
#pragma unroll
    for (int off = 32; off > 0; off >>= 1) s += __shfl_down(s, off);
    __shared__ float ls[4];
    const int lane = t & 63, w = t >> 6;
    if (lane == 0) ls[w] = s;
    __syncthreads();
    if (t == 0) {
        float tot = ls[0] + ls[1] + ls[2] + ls[3];
        invnorm[v] = 1.0f / fmaxf(sqrtf(tot), 1e-12f);
    }
}

__global__ __launch_bounds__(256, 2) void sim_argmax_kernel(
        const float* __restrict__ X, const float* __restrict__ Vg,
        const float* __restrict__ invnorm,
        unsigned long long* __restrict__ rowmax) {
    __shared__ float As[BK][BM + 4];
    __shared__ float Bs[BK][BN + 4];
    const int tid = threadIdx.x;
    const int tx = tid & 15, ty = tid >> 4;
    const int m0 = blockIdx.y * BM, n0 = blockIdx.x * BN;
    const int lr = tid >> 2;            // 0..63
    const int lk = (tid & 3) << 2;      // 0,4,8,12

    const float* Ap0 = X  + (size_t)(m0 + lr) * DIM + lk;
    const float* Ap1 = Ap0 + (size_t)64 * DIM;
    const float* Bp0 = Vg + (size_t)(n0 + lr) * DIM + lk;
    const float* Bp1 = Bp0 + (size_t)64 * DIM;

    float acc[8][8];
#pragma unroll
    for (int i = 0; i < 8; ++i)
#pragma unroll
        for (int j = 0; j < 8; ++j) acc[i][j] = 0.f;

    for (int k0 = 0; k0 < DIM; k0 += BK) {
        float4 a0 = *reinterpret_cast<const float4*>(Ap0 + k0);
        float4 a1 = *reinterpret_cast<const float4*>(Ap1 + k0);
        float4 b0 = *reinterpret_cast<const float4*>(Bp0 + k0);
        float4 b1 = *reinterpret_cast<const float4*>(Bp1 + k0);
        __syncthreads();
        As[lk+0][lr] = a0.x; As[lk+1][lr] = a0.y; As[lk+2][lr] = a0.z; As[lk+3][lr] = a0.w;
        As[lk+0][lr+64] = a1.x; As[lk+1][lr+64] = a1.y; As[lk+2][lr+64] = a1.z; As[lk+3][lr+64] = a1.w;
        Bs[lk+0][lr] = b0.x; Bs[lk+1][lr] = b0.y; Bs[lk+2][lr] = b0.z; Bs[lk+3][lr] = b0.w;
        Bs[lk+0][lr+64] = b1.x; Bs[lk+1][lr+64] = b1.y; Bs[lk+2][lr+64] = b1.z; Bs[lk+3][lr+64] = b1.w;
        __syncthreads();

        // two-level accumulation: local sum over BK, then one add into acc
        float loc[8][8];
#pragma unroll
        for (int i = 0; i < 8; ++i)
#pragma unroll
            for (int j = 0; j < 8; ++j) loc[i][j] = 0.f;

#pragma unroll
        for (int kk = 0; kk < BK; ++kk) {
            float a[8], b[8];
            *reinterpret_cast<float4*>(&a[0]) = *reinterpret_cast<const float4*>(&As[kk][ty*8]);
            *reinterpret_cast<float4*>(&a[4]) = *reinterpret_cast<const float4*>(&As[kk][ty*8+4]);
            *reinterpret_cast<float4*>(&b[0]) = *reinterpret_cast<const float4*>(&Bs[kk][tx*8]);
            *reinterpret_cast<float4*>(&b[4]) = *reinterpret_cast<const float4*>(&Bs[kk][tx*8+4]);
#pragma unroll
            for (int i = 0; i < 8; ++i)
#pragma unroll
                for (int j = 0; j < 8; ++j)
                    loc[i][j] = fmaf(a[i], b[j], loc[i][j]);
        }
#pragma unroll
        for (int i = 0; i < 8; ++i)
#pragma unroll
            for (int j = 0; j < 8; ++j) acc[i][j] += loc[i][j];
    }

    float inv[8];
    *reinterpret_cast<float4*>(&inv[0]) = *reinterpret_cast<const float4*>(invnorm + n0 + tx*8);
    *reinterpret_cast<float4*>(&inv[4]) = *reinterpret_cast<const float4*>(invnorm + n0 + tx*8 + 4);

#pragma unroll
    for (int i = 0; i < 8; ++i) {
        unsigned long long best = 0ull;
#pragma unroll
        for (int j = 0; j < 8; ++j) {
            float v = acc[i][j] * inv[j];
            unsigned long long k = pack_key(v, (unsigned int)(n0 + tx*8 + j));
            best = (k > best) ? k : best;
        }
#pragma unroll
        for (int mask = 1; mask < 16; mask <<= 1) {
            unsigned long long o = __shfl_xor(best, mask);
            best = (o > best) ? o : best;
        }
        if (tx == 0) atomicMax(&rowmax[m0 + ty*8 + i], best);
    }
}

__global__ void finalize_kernel(const float* __restrict__ X, const float* __restrict__ Vg,
                                const unsigned long long* __restrict__ rowmax,
                                float* __restrict__ outx, float* __restrict__ outid) {
    const int r = blockIdx.x;
    const int t = threadIdx.x;
    const unsigned long long key = rowmax[r];
    const unsigned int id = ~(unsigned int)(key & 0xFFFFFFFFull);
    const float* x = X  + (size_t)r * DIM;
    const float* a = Vg + (size_t)id * DIM;
    float4 x0 = *reinterpret_cast<const float4*>(x + t*8);
    float4 x1 = *reinterpret_cast<const float4*>(x + t*8 + 4);
    float4 a0 = *reinterpret_cast<const float4*>(a + t*8);
    float4 a1 = *reinterpret_cast<const float4*>(a + t*8 + 4);
    float4 d0 = make_float4(x0.x-a0.x, x0.y-a0.y, x0.z-a0.z, x0.w-a0.w);
    float4 d1 = make_float4(x1.x-a1.x, x1.y-a1.y, x1.z-a1.z, x1.w-a1.w);
    float so = d0.x*d0.x + d0.y*d0.y + d0.z*d0.z + d0.w*d0.w
             + d1.x*d1.x + d1.y*d1.y + d1.z*d1.z + d1.w*d1.w;
    float sa = a0.x*a0.x + a0.y*a0.y + a0.z*a0.z + a0.w*a0.w
             + a1.x*a1.x + a1.y*a1.y + a1.z*a1.z + a1.w*a1.w;
#pragma unroll
    for (int off = 32; off > 0; off >>= 1) {
        so += __shfl_down(so, off);
        sa += __shfl_down(sa, off);
    }
    __shared__ float lso[4], lsa[4];
    __shared__ float sc;
    const int lane = t & 63, w = t >> 6;
    if (lane == 0) { lso[w] = so; lsa[w] = sa; }
    __syncthreads();
    if (t == 0) {
        float SO = lso[0] + lso[1] + lso[2] + lso[3];
        float SA = lsa[0] + lsa[1] + lsa[2] + lsa[3];
        sc = fminf(0.1f * sqrtf(SA) / (sqrtf(SO) + 1e-8f), 1.0f);
    }
    __syncthreads();
    const float s = sc;
    float4 o0 = make_float4(a0.x + d0.x*s, a0.y + d0.y*s, a0.z + d0.z*s, a0.w + d0.w*s);
    float4 o1 = make_float4(a1.x + d1.x*s, a1.y + d1.y*s, a1.z + d1.z*s, a1.w + d1.w*s);
    float* o = outx + (size_t)r * DIM + t*8;
    *reinterpret_cast<float4*>(o)     = o0;
    *reinterpret_cast<float4*>(o + 4) = o1;
    if (t == 0) outid[r] = (float)id;
}

extern "C" void kernel_launch(void* const* d_in, const int* in_sizes, int n_in,
                              void* d_out, int out_size, void* d_ws, size_t ws_size,
                              hipStream_t stream) {
    const float* X  = (const float*)d_in[0];
    const float* Vg = (const float*)d_in[1];
    const int M  = in_sizes[0] / DIM;   // 8192
    const int NV = in_sizes[1] / DIM;   // 32000

    unsigned long long* rowmax = (unsigned long long*)d_ws;
    float* invnorm = (float*)((char*)d_ws + (size_t)M * sizeof(unsigned long long));

    float* outx  = (float*)d_out;
    float* outid = outx + (size_t)M * DIM;

    hipMemsetAsync(rowmax, 0, (size_t)M * sizeof(unsigned long long), stream);
    vocab_invnorm_kernel<<<NV, 256, 0, stream>>>(Vg, invnorm);

    dim3 grid(NV / BN, M / BM);
    sim_argmax_kernel<<<grid, 256, 0, stream>>>(X, Vg, invnorm, rowmax);

    finalize_kernel<<<M, 256, 0, stream>>>(X, Vg, rowmax, outx, outid);
}

// Round 2
// 3482.323 us; speedup vs baseline: 3.8044x; 3.8044x over previous
//
#include <hip/hip_runtime.h>
#include <hip/hip_bf16.h>

#define DIM 2048
#define BM 128
#define BN 128
#define BK 32
#define KSTEPS (DIM / BK)

typedef _Float16 f16x8 __attribute__((ext_vector_type(8)));
typedef float f32x4 __attribute__((ext_vector_type(4)));

// Monotone float->uint map; pack (val, col) so u64 max = (max val, first col on ties)
__device__ __forceinline__ unsigned long long pack_key(float v, unsigned int col) {
    unsigned int b = __float_as_uint(v);
    b ^= (unsigned int)(((int)b >> 31)) | 0x80000000u;
    return ((unsigned long long)b << 32) | (unsigned long long)(~col);
}

// split 8 f32 -> hi/lo f16 (RNE both; residual ~2^-24 * |x|)
__device__ __forceinline__ void convert8(const float4 u, const float4 v,
                                         f16x8& h, f16x8& l) {
    float x[8] = {u.x, u.y, u.z, u.w, v.x, v.y, v.z, v.w};
#pragma unroll
    for (int e = 0; e < 8; ++e) {
        _Float16 hi = (_Float16)x[e];
        float res = x[e] - (float)hi;
        h[e] = hi;
        l[e] = (_Float16)res;
    }
}

__global__ void vocab_invnorm_kernel(const float* __restrict__ Vg,
                                     float* __restrict__ invnorm) {
    const int v = blockIdx.x;
    const int t = threadIdx.x;
    const float* row = Vg + (size_t)v * DIM;
    float4 f0 = *reinterpret_cast<const float4*>(row + t * 8);
    float4 f1 = *reinterpret_cast<const float4*>(row + t * 8 + 4);
    float s = f0.x*f0.x + f0.y*f0.y + f0.z*f0.z + f0.w*f0.w
            + f1.x*f1.x + f1.y*f1.y + f1.z*f1.z + f1.w*f1.w;
#pragma unroll
    for (int off = 32; off > 0; off >>= 1) s += __shfl_down(s, off);
    __shared__ float ls[4];
    const int lane = t & 63, w = t >> 6;
    if (lane == 0) ls[w] = s;
    __syncthreads();
    if (t == 0) {
        float tot = ls[0] + ls[1] + ls[2] + ls[3];
        invnorm[v] = 1.0f / fmaxf(sqrtf(tot), 1e-12f);
    }
}

__global__ __launch_bounds__(256) void sim_argmax_f16(
        const float* __restrict__ X, const float* __restrict__ Vg,
        const float* __restrict__ invnorm,
        unsigned long long* __restrict__ rowmax) {
    __shared__ _Float16 Ah[BM * BK];
    __shared__ _Float16 Al[BM * BK];
    __shared__ _Float16 Bh[BN * BK];
    __shared__ _Float16 Bl[BN * BK];

    const int tid = threadIdx.x;
    // XCD-chunked bijective swizzle: 16000 blocks, 8 XCDs, 2000 per XCD
    const int flat = blockIdx.x;
    const int idx  = (flat >> 3) + (flat & 7) * 2000;
    const int mblk = idx & 63;          // M fastest: consecutive blocks share B-panel
    const int nblk = idx >> 6;
    const int m0 = mblk * BM, n0 = nblk * BN;

    const int lane = tid & 63;
    const int w  = tid >> 6;
    const int wm = w >> 1, wn = w & 1;  // 2x2 wave grid, 64x64 per wave
    const int lr = lane & 15;           // frag row-within-16
    const int kg = lane >> 4;           // k-group 0..3

    // staging coords: thread covers 8-f32 chunk (sr, skc*8) and (64+sr, skc*8)
    const int sr  = tid >> 2;           // 0..63
    const int skc = tid & 3;            // 0..3

    const float* Aptr0 = X  + (size_t)(m0 + sr)      * DIM + skc * 8;
    const float* Aptr1 = X  + (size_t)(m0 + 64 + sr) * DIM + skc * 8;
    const float* Bptr0 = Vg + (size_t)(n0 + sr)      * DIM + skc * 8;
    const float* Bptr1 = Vg + (size_t)(n0 + 64 + sr) * DIM + skc * 8;

    float4 ra[4], rb[4];
    ra[0] = *(const float4*)(Aptr0);     ra[1] = *(const float4*)(Aptr0 + 4);
    ra[2] = *(const float4*)(Aptr1);     ra[3] = *(const float4*)(Aptr1 + 4);
    rb[0] = *(const float4*)(Bptr0);     rb[1] = *(const float4*)(Bptr0 + 4);
    rb[2] = *(const float4*)(Bptr1);     rb[3] = *(const float4*)(Bptr1 + 4);

    f32x4 acc[4][4] = {};

    const int wofs0 = sr * BK + skc * 8;
    const int wofs1 = (64 + sr) * BK + skc * 8;

    for (int ks = 0; ks < KSTEPS; ++ks) {
        {   // convert + LDS write (waits on the prefetch loads)
            f16x8 h, l;
            convert8(ra[0], ra[1], h, l);
            *(f16x8*)(&Ah[wofs0]) = h;  *(f16x8*)(&Al[wofs0]) = l;
            convert8(ra[2], ra[3], h, l);
            *(f16x8*)(&Ah[wofs1]) = h;  *(f16x8*)(&Al[wofs1]) = l;
            convert8(rb[0], rb[1], h, l);
            *(f16x8*)(&Bh[wofs0]) = h;  *(f16x8*)(&Bl[wofs0]) = l;
            convert8(rb[2], rb[3], h, l);
            *(f16x8*)(&Bh[wofs1]) = h;  *(f16x8*)(&Bl[wofs1]) = l;
        }
        __syncthreads();
        if (ks + 1 < KSTEPS) {  // prefetch next K-step (overlaps MFMA phase)
            const int ko = (ks + 1) * BK;
            ra[0] = *(const float4*)(Aptr0 + ko); ra[1] = *(const float4*)(Aptr0 + ko + 4);
            ra[2] = *(const float4*)(Aptr1 + ko); ra[3] = *(const float4*)(Aptr1 + ko + 4);
            rb[0] = *(const float4*)(Bptr0 + ko); rb[1] = *(const float4*)(Bptr0 + ko + 4);
            rb[2] = *(const float4*)(Bptr1 + ko); rb[3] = *(const float4*)(Bptr1 + ko + 4);
        }
        f16x8 bhf[4], blf[4];
#pragma unroll
        for (int j = 0; j < 4; ++j) {
            const int ofs = (wn * 64 + j * 16 + lr) * BK + kg * 8;
            bhf[j] = *(const f16x8*)(&Bh[ofs]);
            blf[j] = *(const f16x8*)(&Bl[ofs]);
        }
#pragma unroll
        for (int i = 0; i < 4; ++i) {
            const int ofs = (wm * 64 + i * 16 + lr) * BK + kg * 8;
            f16x8 ahf = *(const f16x8*)(&Ah[ofs]);
            f16x8 alf = *(const f16x8*)(&Al[ofs]);
#pragma unroll
            for (int j = 0; j < 4; ++j) {
                acc[i][j] = __builtin_amdgcn_mfma_f32_16x16x32_f16(ahf, bhf[j], acc[i][j], 0, 0, 0);
                acc[i][j] = __builtin_amdgcn_mfma_f32_16x16x32_f16(ahf, blf[j], acc[i][j], 0, 0, 0);
                acc[i][j] = __builtin_amdgcn_mfma_f32_16x16x32_f16(alf, bhf[j], acc[i][j], 0, 0, 0);
            }
        }
        __syncthreads();
    }

    // epilogue: scale by vocab invnorm, fused row-argmax
    float inv[4];
#pragma unroll
    for (int j = 0; j < 4; ++j) inv[j] = invnorm[n0 + wn * 64 + j * 16 + lr];

#pragma unroll
    for (int i = 0; i < 4; ++i) {
#pragma unroll
        for (int r = 0; r < 4; ++r) {
            unsigned long long best = 0ull;
#pragma unroll
            for (int j = 0; j < 4; ++j) {
                const unsigned int col = (unsigned int)(n0 + wn * 64 + j * 16 + lr);
                unsigned long long k = pack_key(acc[i][j][r] * inv[j], col);
                best = (k > best) ? k : best;
            }
#pragma unroll
            for (int mask = 1; mask < 16; mask <<= 1) {
                unsigned long long o = __shfl_xor(best, mask);
                best = (o > best) ? o : best;
            }
            if (lr == 0) {
                const int row = m0 + wm * 64 + i * 16 + kg * 4 + r;
                atomicMax(&rowmax[row], best);
            }
        }
    }
}

__global__ void finalize_kernel(const float* __restrict__ X, const float* __restrict__ Vg,
                                const unsigned long long* __restrict__ rowmax,
                                float* __restrict__ outx, float* __restrict__ outid) {
    const int r = blockIdx.x;
    const int t = threadIdx.x;
    const unsigned long long key = rowmax[r];
    const unsigned int id = ~(unsigned int)(key & 0xFFFFFFFFull);
    const float* x = X  + (size_t)r * DIM;
    const float* a = Vg + (size_t)id * DIM;
    float4 x0 = *reinterpret_cast<const float4*>(x + t*8);
    float4 x1 = *reinterpret_cast<const float4*>(x + t*8 + 4);
    float4 a0 = *reinterpret_cast<const float4*>(a + t*8);
    float4 a1 = *reinterpret_cast<const float4*>(a + t*8 + 4);
    float4 d0 = make_float4(x0.x-a0.x, x0.y-a0.y, x0.z-a0.z, x0.w-a0.w);
    float4 d1 = make_float4(x1.x-a1.x, x1.y-a1.y, x1.z-a1.z, x1.w-a1.w);
    float so = d0.x*d0.x + d0.y*d0.y + d0.z*d0.z + d0.w*d0.w
             + d1.x*d1.x + d1.y*d1.y + d1.z*d1.z + d1.w*d1.w;
    float sa = a0.x*a0.x + a0.y*a0.y + a0.z*a0.z + a0.w*a0.w
             + a1.x*a1.x + a1.y*a1.y + a1.z*a1.z + a1.w*a1.w;
#pragma unroll
    for (int off = 32; off > 0; off >>= 1) {
        so += __shfl_down(so, off);
        sa += __shfl_down(sa, off);
    }
    __shared__ float lso[4], lsa[4];
    __shared__ float sc;
    const int lane = t & 63, w = t >> 6;
    if (lane == 0) { lso[w] = so; lsa[w] = sa; }
    __syncthreads();
    if (t == 0) {
        float SO = lso[0] + lso[1] + lso[2] + lso[3];
        float SA = lsa[0] + lsa[1] + lsa[2] + lsa[3];
        sc = fminf(0.1f * sqrtf(SA) / (sqrtf(SO) + 1e-8f), 1.0f);
    }
    __syncthreads();
    const float s = sc;
    float4 o0 = make_float4(a0.x + d0.x*s, a0.y + d0.y*s, a0.z + d0.z*s, a0.w + d0.w*s);
    float4 o1 = make_float4(a1.x + d1.x*s, a1.y + d1.y*s, a1.z + d1.z*s, a1.w + d1.w*s);
    float* o = outx + (size_t)r * DIM + t*8;
    *reinterpret_cast<float4*>(o)     = o0;
    *reinterpret_cast<float4*>(o + 4) = o1;
    if (t == 0) outid[r] = (float)id;
}

extern "C" void kernel_launch(void* const* d_in, const int* in_sizes, int n_in,
                              void* d_out, int out_size, void* d_ws, size_t ws_size,
                              hipStream_t stream) {
    const float* X  = (const float*)d_in[0];
    const float* Vg = (const float*)d_in[1];
    const int M  = in_sizes[0] / DIM;   // 8192
    const int NV = in_sizes[1] / DIM;   // 32000

    unsigned long long* rowmax = (unsigned long long*)d_ws;
    float* invnorm = (float*)((char*)d_ws + (size_t)M * sizeof(unsigned long long));

    float* outx  = (float*)d_out;
    float* outid = outx + (size_t)M * DIM;

    hipMemsetAsync(rowmax, 0, (size_t)M * sizeof(unsigned long long), stream);
    vocab_invnorm_kernel<<<NV, 256, 0, stream>>>(Vg, invnorm);

    dim3 grid((NV / BN) * (M / BM));    // 16000 blocks, 1D
    sim_argmax_f16<<<grid, 256, 0, stream>>>(X, Vg, invnorm, rowmax);

    finalize_kernel<<<M, 256, 0, stream>>>(X, Vg, rowmax, outx, outid);
}

// Round 3
// 2731.930 us; speedup vs baseline: 4.8494x; 1.2747x over previous
//
#include <hip/hip_runtime.h>
#include <hip/hip_bf16.h>

#define DIM 2048
#define BM 128
#define BN 128
#define BK 32
#define KSTEPS (DIM / BK)

typedef _Float16 f16x8 __attribute__((ext_vector_type(8)));
typedef float f32x4 __attribute__((ext_vector_type(4)));
typedef unsigned long long u64;

// Monotone float->uint map; pack (val, col) so u64 max = (max val, first col on ties)
__device__ __forceinline__ u64 pack_key(float v, unsigned int col) {
    unsigned int b = __float_as_uint(v);
    b ^= (unsigned int)(((int)b >> 31)) | 0x80000000u;
    return ((u64)b << 32) | (u64)(~col);
}
__device__ __forceinline__ u64 umax64(u64 a, u64 b) { return a > b ? a : b; }
__device__ __forceinline__ u64 umin64(u64 a, u64 b) { return a < b ? a : b; }

// lock-free exact top-3 cascade (order-independent => deterministic)
__device__ __forceinline__ void cascade3(u64* r1, u64* r2, u64* r3, u64 k) {
    u64 old = atomicMax(r1, k);
    k = umin64(k, old);
    if (k) {
        old = atomicMax(r2, k);
        k = umin64(k, old);
        if (k) atomicMax(r3, k);
    }
}

// LDS offset with bank swizzle: row*BK + (slot ^ ((row>>1)&3))*8  (f16 elems)
__device__ __forceinline__ int swz(int row, int slot) {
    return row * BK + (slot ^ ((row >> 1) & 3)) * 8;
}

__global__ void vocab_invnorm_kernel(const float* __restrict__ Vg,
                                     float* __restrict__ invnorm) {
    const int v = blockIdx.x;
    const int t = threadIdx.x;
    const float* row = Vg + (size_t)v * DIM;
    float4 f0 = *reinterpret_cast<const float4*>(row + t * 8);
    float4 f1 = *reinterpret_cast<const float4*>(row + t * 8 + 4);
    float s = f0.x*f0.x + f0.y*f0.y + f0.z*f0.z + f0.w*f0.w
            + f1.x*f1.x + f1.y*f1.y + f1.z*f1.z + f1.w*f1.w;
#pragma unroll
    for (int off = 32; off > 0; off >>= 1) s += __shfl_down(s, off);
    __shared__ float ls[4];
    const int lane = t & 63, w = t >> 6;
    if (lane == 0) ls[w] = s;
    __syncthreads();
    if (t == 0) {
        float tot = ls[0] + ls[1] + ls[2] + ls[3];
        invnorm[v] = 1.0f / fmaxf(sqrtf(tot), 1e-12f);
    }
}

__global__ __launch_bounds__(256) void sim_coarse_kernel(
        const float* __restrict__ X, const float* __restrict__ Vg,
        const float* __restrict__ invnorm,
        u64* __restrict__ R1, u64* __restrict__ R2, u64* __restrict__ R3) {
    __shared__ alignas(16) _Float16 Ah[BM * BK];
    __shared__ alignas(16) _Float16 Bh[BN * BK];

    const int tid = threadIdx.x;
    // XCD-chunked bijective swizzle: 16000 blocks, 8 XCDs, 2000 per XCD
    const int flat = blockIdx.x;
    const int idx  = (flat & 7) * 2000 + (flat >> 3);
    // LLC panel ordering: 5 panels of 50 n-blocks; within panel m-fastest
    const int panel = idx / 3200;
    const int w_    = idx - panel * 3200;
    const int mblk  = w_ & 63;
    const int nblk  = panel * 50 + (w_ >> 6);
    const int m0 = mblk * BM, n0 = nblk * BN;

    const int lane = tid & 63;
    const int w  = tid >> 6;
    const int wm = w >> 1, wn = w & 1;  // 2x2 wave grid, 64x64 per wave
    const int lr = lane & 15;           // frag row-within-16
    const int kg = lane >> 4;           // k-chunk 0..3

    // staging coords: thread covers 8-f32 chunk (sr, skc*8) and (64+sr, skc*8)
    const int sr  = tid >> 2;           // 0..63
    const int skc = tid & 3;            // 0..3

    const float* Aptr0 = X  + (size_t)(m0 + sr)      * DIM + skc * 8;
    const float* Aptr1 = X  + (size_t)(m0 + 64 + sr) * DIM + skc * 8;
    const float* Bptr0 = Vg + (size_t)(n0 + sr)      * DIM + skc * 8;
    const float* Bptr1 = Vg + (size_t)(n0 + 64 + sr) * DIM + skc * 8;

    float4 ra[4], rb[4];
    ra[0] = *(const float4*)(Aptr0);     ra[1] = *(const float4*)(Aptr0 + 4);
    ra[2] = *(const float4*)(Aptr1);     ra[3] = *(const float4*)(Aptr1 + 4);
    rb[0] = *(const float4*)(Bptr0);     rb[1] = *(const float4*)(Bptr0 + 4);
    rb[2] = *(const float4*)(Bptr1);     rb[3] = *(const float4*)(Bptr1 + 4);

    f32x4 acc[4][4] = {};

    const int wA0 = swz(sr, skc), wA1 = swz(sr + 64, skc);

    for (int ks = 0; ks < KSTEPS; ++ks) {
        {   // convert hi-f16 + LDS write
            f16x8 h;
            float xv[8];
            *(float4*)(&xv[0]) = ra[0]; *(float4*)(&xv[4]) = ra[1];
#pragma unroll
            for (int e = 0; e < 8; ++e) h[e] = (_Float16)xv[e];
            *(f16x8*)(&Ah[wA0]) = h;
            *(float4*)(&xv[0]) = ra[2]; *(float4*)(&xv[4]) = ra[3];
#pragma unroll
            for (int e = 0; e < 8; ++e) h[e] = (_Float16)xv[e];
            *(f16x8*)(&Ah[wA1]) = h;
            *(float4*)(&xv[0]) = rb[0]; *(float4*)(&xv[4]) = rb[1];
#pragma unroll
            for (int e = 0; e < 8; ++e) h[e] = (_Float16)xv[e];
            *(f16x8*)(&Bh[wA0]) = h;
            *(float4*)(&xv[0]) = rb[2]; *(float4*)(&xv[4]) = rb[3];
#pragma unroll
            for (int e = 0; e < 8; ++e) h[e] = (_Float16)xv[e];
            *(f16x8*)(&Bh[wA1]) = h;
        }
        __syncthreads();
        if (ks + 1 < KSTEPS) {  // prefetch next K-step (overlaps MFMA phase)
            const int ko = (ks + 1) * BK;
            ra[0] = *(const float4*)(Aptr0 + ko); ra[1] = *(const float4*)(Aptr0 + ko + 4);
            ra[2] = *(const float4*)(Aptr1 + ko); ra[3] = *(const float4*)(Aptr1 + ko + 4);
            rb[0] = *(const float4*)(Bptr0 + ko); rb[1] = *(const float4*)(Bptr0 + ko + 4);
            rb[2] = *(const float4*)(Bptr1 + ko); rb[3] = *(const float4*)(Bptr1 + ko + 4);
        }
        f16x8 bhf[4];
#pragma unroll
        for (int j = 0; j < 4; ++j)
            bhf[j] = *(const f16x8*)(&Bh[swz(wn * 64 + j * 16 + lr, kg)]);
#pragma unroll
        for (int i = 0; i < 4; ++i) {
            f16x8 ahf = *(const f16x8*)(&Ah[swz(wm * 64 + i * 16 + lr, kg)]);
#pragma unroll
            for (int j = 0; j < 4; ++j)
                acc[i][j] = __builtin_amdgcn_mfma_f32_16x16x32_f16(ahf, bhf[j], acc[i][j], 0, 0, 0);
        }
        __syncthreads();
    }

    // epilogue: scale by vocab invnorm; per-row block top-2 -> global top-3 cascade
    float inv[4];
#pragma unroll
    for (int j = 0; j < 4; ++j) inv[j] = invnorm[n0 + wn * 64 + j * 16 + lr];

#pragma unroll
    for (int i = 0; i < 4; ++i) {
#pragma unroll
        for (int r = 0; r < 4; ++r) {
            u64 k[4];
#pragma unroll
            for (int j = 0; j < 4; ++j)
                k[j] = pack_key(acc[i][j][r] * inv[j],
                                (unsigned int)(n0 + wn * 64 + j * 16 + lr));
            // per-lane sorted top-2 of 4
            u64 m01 = umax64(k[0], k[1]), n01 = umin64(k[0], k[1]);
            u64 m23 = umax64(k[2], k[3]), n23 = umin64(k[2], k[3]);
            u64 a1 = umax64(m01, m23);
            u64 a2 = umax64(umin64(m01, m23), umax64(n01, n23));
            // butterfly merge across 16 lanes
#pragma unroll
            for (int mask = 1; mask < 16; mask <<= 1) {
                u64 b1 = __shfl_xor(a1, mask);
                u64 b2 = __shfl_xor(a2, mask);
                u64 t1 = umax64(a1, b1);
                a2 = umax64(umin64(a1, b1), umax64(a2, b2));
                a1 = t1;
            }
            if (lr == 0) {
                const int row = m0 + wm * 64 + i * 16 + kg * 4 + r;
                cascade3(&R1[row], &R2[row], &R3[row], a1);
                cascade3(&R1[row], &R2[row], &R3[row], a2);
            }
        }
    }
}

// block-wide sum reduction; returns total to ALL threads
__device__ __forceinline__ float block_sum(float v, float* sbuf, int t) {
#pragma unroll
    for (int off = 32; off > 0; off >>= 1) v += __shfl_down(v, off);
    const int lane = t & 63, w = t >> 6;
    __syncthreads();
    if (lane == 0) sbuf[w] = v;
    __syncthreads();
    return sbuf[0] + sbuf[1] + sbuf[2] + sbuf[3];
}

__global__ void rescue_finalize_kernel(const float* __restrict__ X,
                                       const float* __restrict__ Vg,
                                       const u64* __restrict__ R1,
                                       const u64* __restrict__ R2,
                                       const u64* __restrict__ R3,
                                       float* __restrict__ outx,
                                       float* __restrict__ outid) {
    const int row = blockIdx.x;
    const int t = threadIdx.x;
    __shared__ float sbuf[4];

    int cand[3];
    cand[0] = (int)(~(unsigned int)(R1[row] & 0xFFFFFFFFull));
    cand[1] = (int)(~(unsigned int)(R2[row] & 0xFFFFFFFFull));
    cand[2] = (int)(~(unsigned int)(R3[row] & 0xFFFFFFFFull));

    const float* x = X + (size_t)row * DIM;
    float4 x0 = *reinterpret_cast<const float4*>(x + t * 8);
    float4 x1 = *reinterpret_cast<const float4*>(x + t * 8 + 4);
    float xxp = x0.x*x0.x + x0.y*x0.y + x0.z*x0.z + x0.w*x0.w
              + x1.x*x1.x + x1.y*x1.y + x1.z*x1.z + x1.w*x1.w;
    const float xx = block_sum(xxp, sbuf, t);
    const float xn = fmaxf(sqrtf(xx), 1e-12f);

    u64 bestkey = 0ull;
    int bestid = cand[0];
    float bestsa = 0.f;
#pragma unroll
    for (int c = 0; c < 3; ++c) {
        const float* v = Vg + (size_t)cand[c] * DIM;
        float4 v0 = *reinterpret_cast<const float4*>(v + t * 8);
        float4 v1 = *reinterpret_cast<const float4*>(v + t * 8 + 4);
        float dp = x0.x*v0.x + x0.y*v0.y + x0.z*v0.z + x0.w*v0.w
                 + x1.x*v1.x + x1.y*v1.y + x1.z*v1.z + x1.w*v1.w;
        float vp = v0.x*v0.x + v0.y*v0.y + v0.z*v0.z + v0.w*v0.w
                 + v1.x*v1.x + v1.y*v1.y + v1.z*v1.z + v1.w*v1.w;
        const float dot = block_sum(dp, sbuf, t);
        const float vv  = block_sum(vp, sbuf, t);
        const float s = dot / (xn * fmaxf(sqrtf(vv), 1e-12f));
        u64 key = pack_key(s, (unsigned int)cand[c]);
        if (key > bestkey) { bestkey = key; bestid = cand[c]; bestsa = vv; }
    }

    const float* a = Vg + (size_t)bestid * DIM;
    float4 a0 = *reinterpret_cast<const float4*>(a + t * 8);
    float4 a1 = *reinterpret_cast<const float4*>(a + t * 8 + 4);
    float4 d0 = make_float4(x0.x-a0.x, x0.y-a0.y, x0.z-a0.z, x0.w-a0.w);
    float4 d1 = make_float4(x1.x-a1.x, x1.y-a1.y, x1.z-a1.z, x1.w-a1.w);
    float sop = d0.x*d0.x + d0.y*d0.y + d0.z*d0.z + d0.w*d0.w
              + d1.x*d1.x + d1.y*d1.y + d1.z*d1.z + d1.w*d1.w;
    const float so = block_sum(sop, sbuf, t);
    const float scale = fminf(0.1f * sqrtf(bestsa) / (sqrtf(so) + 1e-8f), 1.0f);

    float4 o0 = make_float4(a0.x + d0.x*scale, a0.y + d0.y*scale,
                            a0.z + d0.z*scale, a0.w + d0.w*scale);
    float4 o1 = make_float4(a1.x + d1.x*scale, a1.y + d1.y*scale,
                            a1.z + d1.z*scale, a1.w + d1.w*scale);
    float* o = outx + (size_t)row * DIM + t * 8;
    *reinterpret_cast<float4*>(o)     = o0;
    *reinterpret_cast<float4*>(o + 4) = o1;
    if (t == 0) outid[row] = (float)bestid;
}

extern "C" void kernel_launch(void* const* d_in, const int* in_sizes, int n_in,
                              void* d_out, int out_size, void* d_ws, size_t ws_size,
                              hipStream_t stream) {
    const float* X  = (const float*)d_in[0];
    const float* Vg = (const float*)d_in[1];
    const int M  = in_sizes[0] / DIM;   // 8192
    const int NV = in_sizes[1] / DIM;   // 32000

    u64* R1 = (u64*)d_ws;
    u64* R2 = R1 + M;
    u64* R3 = R2 + M;
    float* invnorm = (float*)((char*)d_ws + (size_t)3 * M * sizeof(u64));

    float* outx  = (float*)d_out;
    float* outid = outx + (size_t)M * DIM;

    hipMemsetAsync(R1, 0, (size_t)3 * M * sizeof(u64), stream);
    vocab_invnorm_kernel<<<NV, 256, 0, stream>>>(Vg, invnorm);

    dim3 grid((NV / BN) * (M / BM));    // 16000 blocks, 1D
    sim_coarse_kernel<<<grid, 256, 0, stream>>>(X, Vg, invnorm, R1, R2, R3);

    rescue_finalize_kernel<<<M, 256, 0, stream>>>(X, Vg, R1, R2, R3, outx, outid);
}

// Round 4
// 2139.656 us; speedup vs baseline: 6.1918x; 1.2768x over previous
//
#include <hip/hip_runtime.h>
#include <hip/hip_bf16.h>

#define DIM 2048
#define BM 128
#define BN 128
#define BK 32
#define KSTEPS (DIM / BK)      // 64
#define TILE_ELEMS (BM * BK)   // 4096 f16 elems = 8 KB per tile

typedef _Float16 f16x8 __attribute__((ext_vector_type(8)));
typedef float f32x4 __attribute__((ext_vector_type(4)));
typedef unsigned long long u64;

typedef const unsigned int __attribute__((address_space(1))) gu32;
typedef unsigned int __attribute__((address_space(3))) lu32;

__device__ __forceinline__ void gl_lds16(const void* g, void* l) {
    __builtin_amdgcn_global_load_lds((gu32*)g, (lu32*)l, 16, 0, 0);
}

// Monotone float->uint map; pack (val, col) so u64 max = (max val, first col on ties)
__device__ __forceinline__ u64 pack_key(float v, unsigned int col) {
    unsigned int b = __float_as_uint(v);
    b ^= (unsigned int)(((int)b >> 31)) | 0x80000000u;
    return ((u64)b << 32) | (u64)(~col);
}
__device__ __forceinline__ u64 umax64(u64 a, u64 b) { return a > b ? a : b; }
__device__ __forceinline__ u64 umin64(u64 a, u64 b) { return a < b ? a : b; }

// lock-free exact top-3 cascade (order-independent => deterministic)
__device__ __forceinline__ void cascade3(u64* r1, u64* r2, u64* r3, u64 k) {
    u64 old = atomicMax(r1, k);
    k = umin64(k, old);
    if (k) {
        old = atomicMax(r2, k);
        k = umin64(k, old);
        if (k) atomicMax(r3, k);
    }
}

// swizzled elem offset inside a [128][32] f16 tile (0 bank conflicts, verified r3)
__device__ __forceinline__ int swz(int row, int slot) {
    return row * BK + (slot ^ ((row >> 1) & 3)) * 8;
}

__global__ void vocab_invnorm_kernel(const float* __restrict__ Vg,
                                     float* __restrict__ invnorm) {
    const int v = blockIdx.x;
    const int t = threadIdx.x;
    const float* row = Vg + (size_t)v * DIM;
    float4 f0 = *reinterpret_cast<const float4*>(row + t * 8);
    float4 f1 = *reinterpret_cast<const float4*>(row + t * 8 + 4);
    float s = f0.x*f0.x + f0.y*f0.y + f0.z*f0.z + f0.w*f0.w
            + f1.x*f1.x + f1.y*f1.y + f1.z*f1.z + f1.w*f1.w;
#pragma unroll
    for (int off = 32; off > 0; off >>= 1) s += __shfl_down(s, off);
    __shared__ float ls[4];
    const int lane = t & 63, w = t >> 6;
    if (lane == 0) ls[w] = s;
    __syncthreads();
    if (t == 0) {
        float tot = ls[0] + ls[1] + ls[2] + ls[3];
        invnorm[v] = 1.0f / fmaxf(sqrtf(tot), 1e-12f);
    }
}

// X -> tiled+swizzled f16 (raw values)
__global__ void convert_x_kernel(const float* __restrict__ X, _Float16* __restrict__ Xh) {
    const int tile = blockIdx.x;          // mblk*64 + ks
    const int mblk = tile >> 6, ks = tile & 63;
    const float* src = X + (size_t)(mblk * BM) * DIM + ks * BK;
    _Float16* dst = Xh + (size_t)tile * TILE_ELEMS;
    const int t = threadIdx.x;
#pragma unroll
    for (int u = 0; u < 2; ++u) {
        const int c = t + u * 256;        // 0..511
        const int row = c >> 2, slot = c & 3;
        const float* s = src + (size_t)row * DIM + slot * 8;
        float4 f0 = *(const float4*)s, f1 = *(const float4*)(s + 4);
        float xv[8] = {f0.x, f0.y, f0.z, f0.w, f1.x, f1.y, f1.z, f1.w};
        f16x8 h;
#pragma unroll
        for (int e = 0; e < 8; ++e) h[e] = (_Float16)xv[e];
        *(f16x8*)(dst + swz(row, slot)) = h;
    }
}

// V -> tiled+swizzled f16, pre-normalized by invnorm (folds epilogue scaling)
__global__ void convert_v_kernel(const float* __restrict__ Vg,
                                 const float* __restrict__ invnorm,
                                 _Float16* __restrict__ Vh) {
    const int tile = blockIdx.x;          // nblk*64 + ks
    const int nblk = tile >> 6, ks = tile & 63;
    const float* src = Vg + (size_t)(nblk * BN) * DIM + ks * BK;
    _Float16* dst = Vh + (size_t)tile * TILE_ELEMS;
    const int t = threadIdx.x;
#pragma unroll
    for (int u = 0; u < 2; ++u) {
        const int c = t + u * 256;
        const int row = c >> 2, slot = c & 3;
        const float sc = invnorm[nblk * BN + row];
        const float* s = src + (size_t)row * DIM + slot * 8;
        float4 f0 = *(const float4*)s, f1 = *(const float4*)(s + 4);
        float xv[8] = {f0.x, f0.y, f0.z, f0.w, f1.x, f1.y, f1.z, f1.w};
        f16x8 h;
#pragma unroll
        for (int e = 0; e < 8; ++e) h[e] = (_Float16)(xv[e] * sc);
        *(f16x8*)(dst + swz(row, slot)) = h;
    }
}

__global__ __launch_bounds__(256) void sim_f16_tiled(
        const _Float16* __restrict__ Xh, const _Float16* __restrict__ Vh,
        u64* __restrict__ R1, u64* __restrict__ R2, u64* __restrict__ R3) {
    __shared__ alignas(16) _Float16 ldsA[2][TILE_ELEMS];
    __shared__ alignas(16) _Float16 ldsB[2][TILE_ELEMS];

    const int tid = threadIdx.x;
    // XCD-chunked bijective swizzle + LLC panel ordering (verified r3)
    const int flat = blockIdx.x;
    const int idx  = (flat & 7) * 2000 + (flat >> 3);
    const int panel = idx / 3200;
    const int w_    = idx - panel * 3200;
    const int mblk  = w_ & 63;
    const int nblk  = panel * 50 + (w_ >> 6);

    const int lane = tid & 63;
    const int w  = tid >> 6;
    const int wm = w >> 1, wn = w & 1;  // 2x2 wave grid, 64x64 per wave
    const int lr = lane & 15;
    const int kg = lane >> 4;

    const _Float16* Atiles = Xh + (size_t)mblk * KSTEPS * TILE_ELEMS;
    const _Float16* Btiles = Vh + (size_t)nblk * KSTEPS * TILE_ELEMS;

    f32x4 acc[4][4] = {};

    const int so = tid * 8;  // staging elem offset (16B per thread)

    // prologue: stage tile 0 into buffer 0
    gl_lds16(Atiles + so,        &ldsA[0][so]);
    gl_lds16(Atiles + 2048 + so, &ldsA[0][2048 + so]);
    gl_lds16(Btiles + so,        &ldsB[0][so]);
    gl_lds16(Btiles + 2048 + so, &ldsB[0][2048 + so]);
    __syncthreads();

    int cur = 0;
    for (int ks = 0; ks < KSTEPS; ++ks) {
        if (ks + 1 < KSTEPS) {  // stage next tile into other buffer (in flight across compute)
            const _Float16* an = Atiles + (size_t)(ks + 1) * TILE_ELEMS;
            const _Float16* bn = Btiles + (size_t)(ks + 1) * TILE_ELEMS;
            gl_lds16(an + so,        &ldsA[cur ^ 1][so]);
            gl_lds16(an + 2048 + so, &ldsA[cur ^ 1][2048 + so]);
            gl_lds16(bn + so,        &ldsB[cur ^ 1][so]);
            gl_lds16(bn + 2048 + so, &ldsB[cur ^ 1][2048 + so]);
        }
        f16x8 bhf[4];
#pragma unroll
        for (int j = 0; j < 4; ++j)
            bhf[j] = *(const f16x8*)(&ldsB[cur][swz(wn * 64 + j * 16 + lr, kg)]);
#pragma unroll
        for (int i = 0; i < 4; ++i) {
            f16x8 ahf = *(const f16x8*)(&ldsA[cur][swz(wm * 64 + i * 16 + lr, kg)]);
#pragma unroll
            for (int j = 0; j < 4; ++j)
                acc[i][j] = __builtin_amdgcn_mfma_f32_16x16x32_f16(ahf, bhf[j], acc[i][j], 0, 0, 0);
        }
        __syncthreads();   // drains vmcnt (next tile ready) + lgkm; protects dbuf WAR
        cur ^= 1;
    }

    const int m0 = mblk * BM, n0 = nblk * BN;
#pragma unroll
    for (int i = 0; i < 4; ++i) {
#pragma unroll
        for (int r = 0; r < 4; ++r) {
            u64 k[4];
#pragma unroll
            for (int j = 0; j < 4; ++j)
                k[j] = pack_key(acc[i][j][r],
                                (unsigned int)(n0 + wn * 64 + j * 16 + lr));
            u64 m01 = umax64(k[0], k[1]), n01 = umin64(k[0], k[1]);
            u64 m23 = umax64(k[2], k[3]), n23 = umin64(k[2], k[3]);
            u64 a1 = umax64(m01, m23);
            u64 a2 = umax64(umin64(m01, m23), umax64(n01, n23));
#pragma unroll
            for (int mask = 1; mask < 16; mask <<= 1) {
                u64 b1 = __shfl_xor(a1, mask);
                u64 b2 = __shfl_xor(a2, mask);
                u64 t1 = umax64(a1, b1);
                a2 = umax64(umin64(a1, b1), umax64(a2, b2));
                a1 = t1;
            }
            if (lr == 0) {
                const int row = m0 + wm * 64 + i * 16 + kg * 4 + r;
                cascade3(&R1[row], &R2[row], &R3[row], a1);
                cascade3(&R1[row], &R2[row], &R3[row], a2);
            }
        }
    }
}

// ---------------- fallback (verified round-3 path, used if ws too small) ----------------
__global__ __launch_bounds__(256) void sim_coarse_fallback(
        const float* __restrict__ X, const float* __restrict__ Vg,
        const float* __restrict__ invnorm,
        u64* __restrict__ R1, u64* __restrict__ R2, u64* __restrict__ R3) {
    __shared__ alignas(16) _Float16 Ah[BM * BK];
    __shared__ alignas(16) _Float16 Bh[BN * BK];
    const int tid = threadIdx.x;
    const int flat = blockIdx.x;
    const int idx  = (flat & 7) * 2000 + (flat >> 3);
    const int panel = idx / 3200;
    const int w_    = idx - panel * 3200;
    const int mblk  = w_ & 63;
    const int nblk  = panel * 50 + (w_ >> 6);
    const int m0 = mblk * BM, n0 = nblk * BN;
    const int lane = tid & 63;
    const int w  = tid >> 6;
    const int wm = w >> 1, wn = w & 1;
    const int lr = lane & 15;
    const int kg = lane >> 4;
    const int sr  = tid >> 2;
    const int skc = tid & 3;
    const float* Aptr0 = X  + (size_t)(m0 + sr)      * DIM + skc * 8;
    const float* Aptr1 = X  + (size_t)(m0 + 64 + sr) * DIM + skc * 8;
    const float* Bptr0 = Vg + (size_t)(n0 + sr)      * DIM + skc * 8;
    const float* Bptr1 = Vg + (size_t)(n0 + 64 + sr) * DIM + skc * 8;
    float4 ra[4], rb[4];
    ra[0] = *(const float4*)(Aptr0);     ra[1] = *(const float4*)(Aptr0 + 4);
    ra[2] = *(const float4*)(Aptr1);     ra[3] = *(const float4*)(Aptr1 + 4);
    rb[0] = *(const float4*)(Bptr0);     rb[1] = *(const float4*)(Bptr0 + 4);
    rb[2] = *(const float4*)(Bptr1);     rb[3] = *(const float4*)(Bptr1 + 4);
    f32x4 acc[4][4] = {};
    const int wA0 = swz(sr, skc), wA1 = swz(sr + 64, skc);
    for (int ks = 0; ks < KSTEPS; ++ks) {
        {
            f16x8 h; float xv[8];
            *(float4*)(&xv[0]) = ra[0]; *(float4*)(&xv[4]) = ra[1];
#pragma unroll
            for (int e = 0; e < 8; ++e) h[e] = (_Float16)xv[e];
            *(f16x8*)(&Ah[wA0]) = h;
            *(float4*)(&xv[0]) = ra[2]; *(float4*)(&xv[4]) = ra[3];
#pragma unroll
            for (int e = 0; e < 8; ++e) h[e] = (_Float16)xv[e];
            *(f16x8*)(&Ah[wA1]) = h;
            *(float4*)(&xv[0]) = rb[0]; *(float4*)(&xv[4]) = rb[1];
#pragma unroll
            for (int e = 0; e < 8; ++e) h[e] = (_Float16)xv[e];
            *(f16x8*)(&Bh[wA0]) = h;
            *(float4*)(&xv[0]) = rb[2]; *(float4*)(&xv[4]) = rb[3];
#pragma unroll
            for (int e = 0; e < 8; ++e) h[e] = (_Float16)xv[e];
            *(f16x8*)(&Bh[wA1]) = h;
        }
        __syncthreads();
        if (ks + 1 < KSTEPS) {
            const int ko = (ks + 1) * BK;
            ra[0] = *(const float4*)(Aptr0 + ko); ra[1] = *(const float4*)(Aptr0 + ko + 4);
            ra[2] = *(const float4*)(Aptr1 + ko); ra[3] = *(const float4*)(Aptr1 + ko + 4);
            rb[0] = *(const float4*)(Bptr0 + ko); rb[1] = *(const float4*)(Bptr0 + ko + 4);
            rb[2] = *(const float4*)(Bptr1 + ko); rb[3] = *(const float4*)(Bptr1 + ko + 4);
        }
        f16x8 bhf[4];
#pragma unroll
        for (int j = 0; j < 4; ++j)
            bhf[j] = *(const f16x8*)(&Bh[swz(wn * 64 + j * 16 + lr, kg)]);
#pragma unroll
        for (int i = 0; i < 4; ++i) {
            f16x8 ahf = *(const f16x8*)(&Ah[swz(wm * 64 + i * 16 + lr, kg)]);
#pragma unroll
            for (int j = 0; j < 4; ++j)
                acc[i][j] = __builtin_amdgcn_mfma_f32_16x16x32_f16(ahf, bhf[j], acc[i][j], 0, 0, 0);
        }
        __syncthreads();
    }
    float inv[4];
#pragma unroll
    for (int j = 0; j < 4; ++j) inv[j] = invnorm[n0 + wn * 64 + j * 16 + lr];
#pragma unroll
    for (int i = 0; i < 4; ++i) {
#pragma unroll
        for (int r = 0; r < 4; ++r) {
            u64 k[4];
#pragma unroll
            for (int j = 0; j < 4; ++j)
                k[j] = pack_key(acc[i][j][r] * inv[j],
                                (unsigned int)(n0 + wn * 64 + j * 16 + lr));
            u64 m01 = umax64(k[0], k[1]), n01 = umin64(k[0], k[1]);
            u64 m23 = umax64(k[2], k[3]), n23 = umin64(k[2], k[3]);
            u64 a1 = umax64(m01, m23);
            u64 a2 = umax64(umin64(m01, m23), umax64(n01, n23));
#pragma unroll
            for (int mask = 1; mask < 16; mask <<= 1) {
                u64 b1 = __shfl_xor(a1, mask);
                u64 b2 = __shfl_xor(a2, mask);
                u64 t1 = umax64(a1, b1);
                a2 = umax64(umin64(a1, b1), umax64(a2, b2));
                a1 = t1;
            }
            if (lr == 0) {
                const int row = m0 + wm * 64 + i * 16 + kg * 4 + r;
                cascade3(&R1[row], &R2[row], &R3[row], a1);
                cascade3(&R1[row], &R2[row], &R3[row], a2);
            }
        }
    }
}

// block-wide sum reduction; returns total to ALL threads
__device__ __forceinline__ float block_sum(float v, float* sbuf, int t) {
#pragma unroll
    for (int off = 32; off > 0; off >>= 1) v += __shfl_down(v, off);
    const int lane = t & 63, w = t >> 6;
    __syncthreads();
    if (lane == 0) sbuf[w] = v;
    __syncthreads();
    return sbuf[0] + sbuf[1] + sbuf[2] + sbuf[3];
}

__global__ void rescue_finalize_kernel(const float* __restrict__ X,
                                       const float* __restrict__ Vg,
                                       const u64* __restrict__ R1,
                                       const u64* __restrict__ R2,
                                       const u64* __restrict__ R3,
                                       float* __restrict__ outx,
                                       float* __restrict__ outid) {
    const int row = blockIdx.x;
    const int t = threadIdx.x;
    __shared__ float sbuf[4];

    int cand[3];
    cand[0] = (int)(~(unsigned int)(R1[row] & 0xFFFFFFFFull));
    cand[1] = (int)(~(unsigned int)(R2[row] & 0xFFFFFFFFull));
    cand[2] = (int)(~(unsigned int)(R3[row] & 0xFFFFFFFFull));

    const float* x = X + (size_t)row * DIM;
    float4 x0 = *reinterpret_cast<const float4*>(x + t * 8);
    float4 x1 = *reinterpret_cast<const float4*>(x + t * 8 + 4);
    float xxp = x0.x*x0.x + x0.y*x0.y + x0.z*x0.z + x0.w*x0.w
              + x1.x*x1.x + x1.y*x1.y + x1.z*x1.z + x1.w*x1.w;
    const float xx = block_sum(xxp, sbuf, t);
    const float xn = fmaxf(sqrtf(xx), 1e-12f);

    u64 bestkey = 0ull;
    int bestid = cand[0];
    float bestsa = 0.f;
#pragma unroll
    for (int c = 0; c < 3; ++c) {
        const float* v = Vg + (size_t)cand[c] * DIM;
        float4 v0 = *reinterpret_cast<const float4*>(v + t * 8);
        float4 v1 = *reinterpret_cast<const float4*>(v + t * 8 + 4);
        float dp = x0.x*v0.x + x0.y*v0.y + x0.z*v0.z + x0.w*v0.w
                 + x1.x*v1.x + x1.y*v1.y + x1.z*v1.z + x1.w*v1.w;
        float vp = v0.x*v0.x + v0.y*v0.y + v0.z*v0.z + v0.w*v0.w
                 + v1.x*v1.x + v1.y*v1.y + v1.z*v1.z + v1.w*v1.w;
        const float dot = block_sum(dp, sbuf, t);
        const float vv  = block_sum(vp, sbuf, t);
        const float s = dot / (xn * fmaxf(sqrtf(vv), 1e-12f));
        u64 key = pack_key(s, (unsigned int)cand[c]);
        if (key > bestkey) { bestkey = key; bestid = cand[c]; bestsa = vv; }
    }

    const float* a = Vg + (size_t)bestid * DIM;
    float4 a0 = *reinterpret_cast<const float4*>(a + t * 8);
    float4 a1 = *reinterpret_cast<const float4*>(a + t * 8 + 4);
    float4 d0 = make_float4(x0.x-a0.x, x0.y-a0.y, x0.z-a0.z, x0.w-a0.w);
    float4 d1 = make_float4(x1.x-a1.x, x1.y-a1.y, x1.z-a1.z, x1.w-a1.w);
    float sop = d0.x*d0.x + d0.y*d0.y + d0.z*d0.z + d0.w*d0.w
              + d1.x*d1.x + d1.y*d1.y + d1.z*d1.z + d1.w*d1.w;
    const float so = block_sum(sop, sbuf, t);
    const float scale = fminf(0.1f * sqrtf(bestsa) / (sqrtf(so) + 1e-8f), 1.0f);

    float4 o0 = make_float4(a0.x + d0.x*scale, a0.y + d0.y*scale,
                            a0.z + d0.z*scale, a0.w + d0.w*scale);
    float4 o1 = make_float4(a1.x + d1.x*scale, a1.y + d1.y*scale,
                            a1.z + d1.z*scale, a1.w + d1.w*scale);
    float* o = outx + (size_t)row * DIM + t * 8;
    *reinterpret_cast<float4*>(o)     = o0;
    *reinterpret_cast<float4*>(o + 4) = o1;
    if (t == 0) outid[row] = (float)bestid;
}

extern "C" void kernel_launch(void* const* d_in, const int* in_sizes, int n_in,
                              void* d_out, int out_size, void* d_ws, size_t ws_size,
                              hipStream_t stream) {
    const float* X  = (const float*)d_in[0];
    const float* Vg = (const float*)d_in[1];
    const int M  = in_sizes[0] / DIM;   // 8192
    const int NV = in_sizes[1] / DIM;   // 32000

    char* ws = (char*)d_ws;
    u64* R1 = (u64*)ws;
    u64* R2 = R1 + M;
    u64* R3 = R2 + M;
    size_t off = (size_t)3 * M * sizeof(u64);           // 196608
    float* invnorm = (float*)(ws + off);
    off += ((size_t)NV * sizeof(float) + 255) & ~255ull; // 128000 -> 128256 pad
    _Float16* Xh = (_Float16*)(ws + off);
    off += (size_t)M * DIM * sizeof(_Float16);           // 32 MB
    _Float16* Vh = (_Float16*)(ws + off);
    off += (size_t)NV * DIM * sizeof(_Float16);          // 128 MB
    const bool fast = (ws_size >= off);

    float* outx  = (float*)d_out;
    float* outid = outx + (size_t)M * DIM;

    hipMemsetAsync(R1, 0, (size_t)3 * M * sizeof(u64), stream);
    vocab_invnorm_kernel<<<NV, 256, 0, stream>>>(Vg, invnorm);

    dim3 grid((NV / BN) * (M / BM));    // 16000 blocks
    if (fast) {
        convert_x_kernel<<<(M / BM) * KSTEPS, 256, 0, stream>>>(X, Xh);
        convert_v_kernel<<<(NV / BN) * KSTEPS, 256, 0, stream>>>(Vg, invnorm, Vh);
        sim_f16_tiled<<<grid, 256, 0, stream>>>(Xh, Vh, R1, R2, R3);
    } else {
        sim_coarse_fallback<<<grid, 256, 0, stream>>>(X, Vg, invnorm, R1, R2, R3);
    }

    rescue_finalize_kernel<<<M, 256, 0, stream>>>(X, Vg, R1, R2, R3, outx, outid);
}